// Round 8
// baseline (906.536 us; speedup 1.0000x reference)
//
#include <hip/hip_runtime.h>

// Problem constants (from reference)
constexpr int B_     = 4;
constexpr int N_UP   = 16384;
constexpr int N_DOWN = 4096;
constexpr int C_UP_  = 384;
constexpr int C_DOWN_= 512;
constexpr int C_OUT_ = 512;

// Spatial grid for exact KNN
constexpr int   GRID  = 32;
constexpr int   GRID3 = GRID * GRID * GRID;       // 32768 cells
constexpr float GLO   = -5.12f;
constexpr float GH    = 0.32f;
constexpr float GINV  = 3.125f;                   // 1/GH (exact f32)
constexpr int   CAP   = 48;                       // bucket capacity (P(overflow)~1e-20)

// Fused knn+cvt dispatch geometry
constexpr int KNN_BLOCKS     = (B_ * N_UP) / 256;                // 256
constexpr int CVT_BLOCKS_TOT = 24576 + 8192 + 192 + 256;         // 33216

typedef __attribute__((ext_vector_type(8))) short bf16x8;
typedef __attribute__((ext_vector_type(4))) float f32x4;

// f32 -> bf16 round-to-nearest-even (bit-exact, no API dependence)
__device__ inline unsigned short f2bf(float f) {
    unsigned int u = __float_as_uint(f);
    return (unsigned short)((u + 0x7FFFu + ((u >> 16) & 1u)) >> 16);
}

// async global->LDS, 16B per lane. HW: dest = wave-uniform base + lane*16.
__device__ inline void load_lds_128(const void* g, void* l) {
    __builtin_amdgcn_global_load_lds(
        (const __attribute__((address_space(1))) unsigned int*)g,
        (__attribute__((address_space(3))) unsigned int*)l, 16, 0, 0);
}

__device__ inline int cellc(float v) {
    int c = (int)floorf((v - GLO) * GINV);
    return min(max(c, 0), GRID - 1);
}

// ---------------------------------------------------------------------------
// zero the per-cell counters (B_*GRID3 ints), int4 per thread
// ---------------------------------------------------------------------------
__global__ void zero_cnt(int4* __restrict__ cnt4) {
    cnt4[blockIdx.x * 256 + threadIdx.x] = int4{0, 0, 0, 0};
}

// ---------------------------------------------------------------------------
// pts4[b][m] = {x, y, z, (x*x+y*y)+z*z} (ref rounding order, no contract)
// + scatter point into its grid bucket (atomic slot).
// Bucket order is nondeterministic; selection below is order-independent
// (lexicographic (d, idx) insert), so results are deterministic.
// ---------------------------------------------------------------------------
__global__ void prep_build(const float* __restrict__ down_pts,
                           float4* __restrict__ pts4,
                           int* __restrict__ cnt, int* __restrict__ bucket) {
#pragma clang fp contract(off)
    const int i = blockIdx.x * 256 + threadIdx.x;   // 0 .. B*N_DOWN-1
    const float x = down_pts[i * 3 + 0];
    const float y = down_pts[i * 3 + 1];
    const float z = down_pts[i * 3 + 2];
    float4 p; p.x = x; p.y = y; p.z = z; p.w = (x * x + y * y) + z * z;
    pts4[i] = p;

    const int b = i >> 12;                           // N_DOWN = 4096
    const int m = i & (N_DOWN - 1);                  // local point index
    const int cell = (cellc(x) * GRID + cellc(y)) * GRID + cellc(z);
    const int slot = atomicAdd(&cnt[b * GRID3 + cell], 1);
    if (slot < CAP) bucket[(size_t)(b * GRID3 + cell) * CAP + slot] = m;
}

// ---------------------------------------------------------------------------
// FUSED: exact grid-KNN (blocks [0,256)) + f32->bf16 cvt (rest).
//
// KNN: per query, scan expanding Chebyshev shells of the grid. Stop when
// d2 < (r*GH)^2 * 0.999 (conservative: any unscanned point is >= r*GH away;
// clamped cells only move points/queries outward of their box so the bound
// still holds; margin covers ulp-level rounding). Hard cap r<=31 scans the
// whole grid -> unconditionally exact. Per-pair distance is the byte-exact
// expression of the (7x passing) brute version; tie-break is lexicographic
// (d, idx), equivalent to the stable ascending-index scan.
//
// cvt blocks provide the occupancy that hides knn's divergent gather latency.
// ---------------------------------------------------------------------------
__launch_bounds__(256, 4)
__global__ void knn_grid_cvt(const float* __restrict__ up_pts,   // [B,N_UP,3]
                             const float4* __restrict__ pts4,    // [B,N_DOWN]
                             const int* __restrict__ cnt,
                             const int* __restrict__ bucket,
                             int*   __restrict__ idx_out,        // [B*N_UP,3]
                             float* __restrict__ w_out,          // [B*N_UP,3]
                             const float* __restrict__ s_upf, unsigned short* __restrict__ d_upf,
                             const float* __restrict__ s_dnf, unsigned short* __restrict__ d_dnf,
                             const float* __restrict__ s_wup, unsigned short* __restrict__ d_wup,
                             const float* __restrict__ s_wdn, unsigned short* __restrict__ d_wdn)
{
    if (blockIdx.x < KNN_BLOCKS) {
#pragma clang fp contract(off)
        const int t = blockIdx.x * 256 + threadIdx.x;   // 0 .. B*N_UP-1
        const int b = t >> 14;                          // N_UP = 16384

        const float qx = up_pts[(size_t)t * 3 + 0];
        const float qy = up_pts[(size_t)t * 3 + 1];
        const float qz = up_pts[(size_t)t * 3 + 2];
        const float qu = (qx * qx + qy * qy) + qz * qz;

        const int cx = cellc(qx), cy = cellc(qy), cz = cellc(qz);
        const int*    ccnt = cnt + b * GRID3;
        const int*    cbkt = bucket + (size_t)b * GRID3 * CAP;
        const float4* pp   = pts4 + (size_t)b * N_DOWN;

        float d0 = 1e30f, d1 = 1e30f, d2 = 1e30f;
        int   i0 = 0,     i1 = 0,     i2 = 0;

#define SCAN_CELL(X, Y, Z)                                                  \
        {                                                                   \
            const int cid = ((X) * GRID + (Y)) * GRID + (Z);                \
            const int n   = min(ccnt[cid], CAP);                            \
            const int* bk = cbkt + (size_t)cid * CAP;                       \
            for (int j = 0; j < n; ++j) {                                   \
                const int m = bk[j];                                        \
                const float4 p = pp[m];                                     \
                const float cr = (qx * p.x + qy * p.y) + qz * p.z;          \
                const float d  = __builtin_fmaf(-2.0f, cr, qu + p.w);       \
                const bool c2 = (d < d2) | ((d == d2) & (m < i2));          \
                const bool c1 = (d < d1) | ((d == d1) & (m < i1));          \
                const bool c0 = (d < d0) | ((d == d0) & (m < i0));          \
                { const int tt = c2 ? m : i2; i2 = c1 ? i1 : tt; }          \
                { const int tt = c1 ? m : i1; i1 = c0 ? i0 : tt; }          \
                i0 = c0 ? m : i0;                                           \
                const float n1 = __builtin_amdgcn_fmed3f(d, d0, d1);        \
                const float n2 = __builtin_amdgcn_fmed3f(d, d1, d2);        \
                d0 = fminf(d0, d); d1 = n1; d2 = n2;                        \
            }                                                               \
        }

        for (int r = 0; r < GRID; ++r) {
            const int x0 = max(cx - r, 0), x1 = min(cx + r, GRID - 1);
            const int y0 = max(cy - r, 0), y1 = min(cy + r, GRID - 1);
            const int z0 = max(cz - r, 0), z1 = min(cz + r, GRID - 1);
            for (int x = x0; x <= x1; ++x) {
                const int axa = (x - cx) < 0 ? (cx - x) : (x - cx);
                for (int y = y0; y <= y1; ++y) {
                    const int aya = (y - cy) < 0 ? (cy - y) : (y - cy);
                    const int m2 = axa > aya ? axa : aya;
                    if (m2 == r) {
                        for (int z = z0; z <= z1; ++z) SCAN_CELL(x, y, z);
                    } else {
                        if (cz - r >= 0)        SCAN_CELL(x, y, cz - r);
                        if (cz + r <= GRID - 1) SCAN_CELL(x, y, cz + r);
                    }
                }
            }
            const float rr = (float)r * GH;
            if (d2 < rr * rr * 0.999f) break;   // 3 found (d2<inf) & shell bound
        }
#undef SCAN_CELL

        const float w0 = 1.0f / (d0 + 1e-8f);
        const float w1 = 1.0f / (d1 + 1e-8f);
        const float w2 = 1.0f / (d2 + 1e-8f);
        const float s  = (w0 + w1) + w2;
        idx_out[(size_t)t * 3 + 0] = i0;
        idx_out[(size_t)t * 3 + 1] = i1;
        idx_out[(size_t)t * 3 + 2] = i2;
        w_out[(size_t)t * 3 + 0] = w0 / s;
        w_out[(size_t)t * 3 + 1] = w1 / s;
        w_out[(size_t)t * 3 + 2] = w2 / s;
    } else {
        // cvt path: 1024 f32 elements per block, block-uniform buffer select
        const int blk = blockIdx.x - KNN_BLOCKS;
        const float* s; unsigned short* d; size_t base;
        if (blk < 24576)      { s = s_upf; d = d_upf; base = (size_t)blk * 1024; }
        else if (blk < 32768) { s = s_dnf; d = d_dnf; base = (size_t)(blk - 24576) * 1024; }
        else if (blk < 32960) { s = s_wup; d = d_wup; base = (size_t)(blk - 32768) * 1024; }
        else                  { s = s_wdn; d = d_wdn; base = (size_t)(blk - 32960) * 1024; }
        const size_t i = base / 4 + threadIdx.x;   // float4 index
        const float4 v = ((const float4*)s)[i];
        ushort4 o;
        o.x = f2bf(v.x); o.y = f2bf(v.y); o.z = f2bf(v.z); o.w = f2bf(v.w);
        ((ushort4*)d)[i] = o;
    }
}

// ---------------------------------------------------------------------------
// bf16 MFMA GEMM: C[m,n] = sum_k A[m,k]*W[n,k] (+bias) (+interp gather)
// 128x128 tile, BK=64, 256 threads = 4 waves (2x2 of 64x64), 16x16x32 MFMA,
// width-16 global_load_lds staging.  (byte-identical to R7)
// ---------------------------------------------------------------------------
template<bool INTERP>
__launch_bounds__(256)
__global__ void gemm_bf16(const unsigned short* __restrict__ A,  // [M,K] bf16
                          const unsigned short* __restrict__ W,  // [N,K] bf16
                          const float* __restrict__ bias,        // [N]
                          float* __restrict__ C,                 // [M,N] f32
                          const int K, const int N,
                          const int* __restrict__ knn_idx,       // [M,3]
                          const float* __restrict__ knn_w,       // [M,3]
                          const float* __restrict__ down_f)      // [B*N_DOWN,N]
{
    __shared__ __align__(16) unsigned short As[128 * 64];   // 16 KB
    __shared__ __align__(16) unsigned short Bs[128 * 64];   // 16 KB
    __shared__ int   sI[128 * 3];
    __shared__ float sV[128 * 3];

    const int tid  = threadIdx.x;
    const int lane = tid & 63;
    const int wv   = tid >> 6;
    const int wrow = (wv >> 1) * 64;
    const int wcol = (wv & 1) * 64;
    const int quad = lane >> 4;
    const int l16  = lane & 15;
    const int m0   = blockIdx.y * 128;
    const int n0   = blockIdx.x * 128;

    if (INTERP) {
        for (int t = tid; t < 384; t += 256) {
            sI[t] = knn_idx[(size_t)m0 * 3 + t];
            sV[t] = knn_w[(size_t)m0 * 3 + t];
        }
    }

    f32x4 acc[4][4];
#pragma unroll
    for (int i = 0; i < 4; ++i)
#pragma unroll
        for (int j = 0; j < 4; ++j) {
            acc[i][j][0] = 0.f; acc[i][j][1] = 0.f;
            acc[i][j][2] = 0.f; acc[i][j][3] = 0.f;
        }

    // staging geometry: LDS tile is [row][64k] bf16 (128 B rows); each wave
    // covers 4 KiB (32 rows) as four 1 KiB chunks of lane*16.
    const int o0 = wv * 4096 + lane * 16;
    const char* Ab = (const char*)A;
    const char* Wb = (const char*)W;
    const size_t Ks = (size_t)K;

    for (int k0 = 0; k0 < K; k0 += 64) {
        __syncthreads();   // previous iter's ds_reads done before overwrite
#pragma unroll
        for (int c = 0; c < 4; ++c) {
            const int o = o0 + c * 1024;
            const int r = o >> 7, kb = o & 127;
            load_lds_128(Ab + ((size_t)(m0 + r) * Ks + k0) * 2 + kb, (char*)As + o);
            load_lds_128(Wb + ((size_t)(n0 + r) * Ks + k0) * 2 + kb, (char*)Bs + o);
        }
        __syncthreads();   // vmcnt(0) drained by compiler before barrier

#pragma unroll
        for (int kk = 0; kk < 2; ++kk) {
            bf16x8 af[4], bw[4];
#pragma unroll
            for (int i = 0; i < 4; ++i)
                af[i] = *(const bf16x8*)(As + (wrow + i * 16 + l16) * 64 + kk * 32 + quad * 8);
#pragma unroll
            for (int j = 0; j < 4; ++j)
                bw[j] = *(const bf16x8*)(Bs + (wcol + j * 16 + l16) * 64 + kk * 32 + quad * 8);
#pragma unroll
            for (int i = 0; i < 4; ++i)
#pragma unroll
                for (int j = 0; j < 4; ++j)
                    acc[i][j] = __builtin_amdgcn_mfma_f32_16x16x32_bf16(
                        af[i], bw[j], acc[i][j], 0, 0, 0);
        }
    }

    float bv[4];
#pragma unroll
    for (int j = 0; j < 4; ++j) bv[j] = bias[n0 + wcol + j * 16 + l16];

#pragma unroll
    for (int i = 0; i < 4; ++i) {
#pragma unroll
        for (int r = 0; r < 4; ++r) {
            const int row = m0 + wrow + i * 16 + quad * 4 + r;  // C/D: row=quad*4+reg
            float* crow = C + (size_t)row * N;
            if (INTERP) {
                const int lr3  = (row - m0) * 3;
                const int base = (row >> 14) * N_DOWN;          // batch * N_DOWN
                const float w0 = sV[lr3 + 0], w1 = sV[lr3 + 1], w2 = sV[lr3 + 2];
                const float* f0 = down_f + (size_t)(base + sI[lr3 + 0]) * N;
                const float* f1 = down_f + (size_t)(base + sI[lr3 + 1]) * N;
                const float* f2 = down_f + (size_t)(base + sI[lr3 + 2]) * N;
#pragma unroll
                for (int j = 0; j < 4; ++j) {
                    const int c = n0 + wcol + j * 16 + l16;     // C/D: col=lane&15
                    crow[c] = acc[i][j][r] + bv[j] + w0 * f0[c] + w1 * f1[c] + w2 * f2[c];
                }
            } else {
#pragma unroll
                for (int j = 0; j < 4; ++j) {
                    const int c = n0 + wcol + j * 16 + l16;
                    crow[c] = acc[i][j][r] + bv[j];
                }
            }
        }
    }
}

// ---------------------------------------------------------------------------
extern "C" void kernel_launch(void* const* d_in, const int* in_sizes, int n_in,
                              void* d_out, int out_size, void* d_ws, size_t ws_size,
                              hipStream_t stream) {
    const float* up_points     = (const float*)d_in[0];
    const float* up_features   = (const float*)d_in[1];
    const float* down_points   = (const float*)d_in[2];
    const float* down_features = (const float*)d_in[3];
    const float* W_up          = (const float*)d_in[4];
    const float* b_up          = (const float*)d_in[5];
    const float* W_down        = (const float*)d_in[6];
    const float* b_down        = (const float*)d_in[7];
    float* out = (float*)d_out;

    // workspace layout (all offsets 256B-aligned by construction)
    char* ws = (char*)d_ws;
    size_t off = 0;
    float* down_f = (float*)(ws + off);             off += (size_t)B_ * N_DOWN * C_OUT_ * 4;      // 33.6 MB
    int*   knn_idx = (int*)(ws + off);              off += (size_t)B_ * N_UP * 3 * 4;             // 0.8 MB
    float* knn_w   = (float*)(ws + off);            off += (size_t)B_ * N_UP * 3 * 4;             // 0.8 MB
    int*   cnt     = (int*)(ws + off);              off += (size_t)B_ * GRID3 * 4;                // 0.5 MB
    int*   bucket  = (int*)(ws + off);              off += (size_t)B_ * GRID3 * CAP * 4;          // 25.2 MB
    float4* pts4   = (float4*)(ws + off);           off += (size_t)B_ * N_DOWN * 16;              // 0.26 MB
    unsigned short* upf_bf = (unsigned short*)(ws + off); off += (size_t)B_ * N_UP * C_UP_ * 2;   // 50.3 MB
    unsigned short* dnf_bf = (unsigned short*)(ws + off); off += (size_t)B_ * N_DOWN * C_DOWN_ * 2; // 16.8 MB
    unsigned short* wup_bf = (unsigned short*)(ws + off); off += (size_t)C_OUT_ * C_UP_ * 2;      // 0.4 MB
    unsigned short* wdn_bf = (unsigned short*)(ws + off); off += (size_t)C_OUT_ * C_DOWN_ * 2;    // 0.5 MB

    // 1) zero grid counters, then prep pts4 + scatter into buckets
    zero_cnt<<<(B_ * GRID3) / 1024, 256, 0, stream>>>((int4*)cnt);
    prep_build<<<(B_ * N_DOWN) / 256, 256, 0, stream>>>(down_points, pts4, cnt, bucket);

    // 2) fused exact grid-KNN + all f32->bf16 conversions (one dispatch)
    knn_grid_cvt<<<KNN_BLOCKS + CVT_BLOCKS_TOT, 256, 0, stream>>>(
        up_points, pts4, cnt, bucket, knn_idx, knn_w,
        up_features, upf_bf, down_features, dnf_bf, W_up, wup_bf, W_down, wdn_bf);

    // 3) down_f = down_features @ W_down^T + b_down   [B*N_DOWN, 512]
    gemm_bf16<false><<<dim3(C_OUT_ / 128, (B_ * N_DOWN) / 128), 256, 0, stream>>>(
        dnf_bf, wdn_bf, b_down, down_f, C_DOWN_, C_OUT_, nullptr, nullptr, nullptr);

    // 4) out = up_features @ W_up^T + b_up + interp(down_f)   [B*N_UP, 512]
    gemm_bf16<true><<<dim3(C_OUT_ / 128, (B_ * N_UP) / 128), 256, 0, stream>>>(
        upf_bf, wup_bf, b_up, out, C_UP_, C_OUT_, knn_idx, knn_w, down_f);
}

// Round 9
// 472.972 us; speedup vs baseline: 1.9167x; 1.9167x over previous
//
#include <hip/hip_runtime.h>

// Problem constants (from reference)
constexpr int B_     = 4;
constexpr int N_UP   = 16384;
constexpr int N_DOWN = 4096;
constexpr int C_UP_  = 384;
constexpr int C_DOWN_= 512;
constexpr int C_OUT_ = 512;

// KNN chunking (R5 brute structure: locally converged at 134us)
constexpr int S_CHUNKS = 16;               // candidate chunks
constexpr int CH       = N_DOWN / S_CHUNKS; // 256 candidates per chunk

// Fused dispatch geometry: knn blocks first, gemm<false> blocks backfill
constexpr int KNN_BLOCKS = (N_UP / 512) * B_ * S_CHUNKS;             // 2048
constexpr int GF_BLOCKS  = (C_OUT_ / 128) * ((B_ * N_DOWN) / 128);   // 512

typedef __attribute__((ext_vector_type(8))) short bf16x8;
typedef __attribute__((ext_vector_type(4))) float f32x4;
typedef __attribute__((ext_vector_type(4))) float f4v;

// f32 -> bf16 round-to-nearest-even (bit-exact; same function the cvt pass
// used in R0-R7, so LDS contents fed to MFMA are bit-identical)
__device__ inline unsigned short f2bf(float f) {
    unsigned int u = __float_as_uint(f);
    return (unsigned short)((u + 0x7FFFu + ((u >> 16) & 1u)) >> 16);
}

// pack 8 f32 -> 8 bf16 (4 dwords) for one ds_write_b128
__device__ inline uint4 pack8(float4 a, float4 b) {
    uint4 o;
    o.x = (unsigned)f2bf(a.x) | ((unsigned)f2bf(a.y) << 16);
    o.y = (unsigned)f2bf(a.z) | ((unsigned)f2bf(a.w) << 16);
    o.z = (unsigned)f2bf(b.x) | ((unsigned)f2bf(b.y) << 16);
    o.w = (unsigned)f2bf(b.z) | ((unsigned)f2bf(b.w) << 16);
    return o;
}

// ---------------------------------------------------------------------------
// pts4[b][m] = {x, y, z, (x*x+y*y)+z*z}   (ref rounding order, no contract)
// ---------------------------------------------------------------------------
__global__ void prep_pts4(const float* __restrict__ down_pts, float4* __restrict__ pts4) {
#pragma clang fp contract(off)
    const int i = blockIdx.x * 256 + threadIdx.x;   // 0 .. B*N_DOWN-1
    const float x = down_pts[i * 3 + 0];
    const float y = down_pts[i * 3 + 1];
    const float z = down_pts[i * 3 + 2];
    float4 p; p.x = x; p.y = y; p.z = z; p.w = (x * x + y * y) + z * z;
    pts4[i] = p;
}

// ---------------------------------------------------------------------------
// FUSED: brute knn chunk scan (blocks [0,2048)) + down-GEMM (blocks [2048,2560)).
// Independent work, block-uniform branch. knn first (the long pole), gemm
// backfills CU slots. Fused-kernel resources (~100 VGPR, 32KB LDS) still give
// 4 blocks/CU = 16 waves/CU -- the occupancy knn had standalone.
//
// knn body: byte-identical to the R5/R6/R7 passing version.
// gemm body: C[m,n] = sum_k dnf[m,k]*Wdn[n,k] + b_down[n], K=512, N=512,
//   staged from f32 with inline f2bf (bit-identical LDS contents vs R7).
// ---------------------------------------------------------------------------
__launch_bounds__(256)
__global__ void knn_gdown(const float* __restrict__ up_pts,   // [B,N_UP,3]
                          const float4* __restrict__ pts4,    // [B,N_DOWN]
                          float* __restrict__ part_d,         // [B*N_UP, S*3]
                          int*   __restrict__ part_i,
                          const float* __restrict__ Af,       // down_features f32 [B*N_DOWN, 512]
                          const float* __restrict__ Wf,       // W_down f32 [512, 512]
                          const float* __restrict__ bias,     // b_down
                          float* __restrict__ C)              // down_f f32 [B*N_DOWN, 512]
{
    __shared__ __align__(16) unsigned short As[128 * 64];   // 16 KB
    __shared__ __align__(16) unsigned short Bs[128 * 64];   // 16 KB

    if (blockIdx.x < KNN_BLOCKS) {
#pragma clang fp contract(off)
        const int kb = blockIdx.x;
        const int b  = (kb >> 5) & 3;
        const int s  = kb >> 7;
        const int mbase = s * CH;

        typedef __attribute__((address_space(4))) const f4v cst_f4;
        const cst_f4* sp = (const cst_f4*)(pts4 + (size_t)b * N_DOWN + mbase);

        const int n0 = (kb & 31) * 512;
        const int g0 = b * N_UP + n0 + threadIdx.x;
        const int g1 = g0 + 256;

        const float ax = up_pts[(size_t)g0 * 3 + 0];
        const float ay = up_pts[(size_t)g0 * 3 + 1];
        const float az = up_pts[(size_t)g0 * 3 + 2];
        const float au = (ax * ax + ay * ay) + az * az;
        const float bx = up_pts[(size_t)g1 * 3 + 0];
        const float by = up_pts[(size_t)g1 * 3 + 1];
        const float bz = up_pts[(size_t)g1 * 3 + 2];
        const float bu = (bx * bx + by * by) + bz * bz;

        float a0 = 1e30f, a1 = 1e30f, a2 = 1e30f;  int ia0 = 0, ia1 = 0, ia2 = 0;
        float b0 = 1e30f, b1 = 1e30f, b2 = 1e30f;  int ib0 = 0, ib1 = 0, ib2 = 0;

        // prefetch double-buffer: group of 4 candidates = 64B scalar load
        f4v c0 = sp[0], c1 = sp[1], c2 = sp[2], c3 = sp[3];

#define PAIR(P, GI)                                                        \
        {                                                                  \
            const float cra = (ax * (P).x + ay * (P).y) + az * (P).z;      \
            const float da  = __builtin_fmaf(-2.0f, cra, au + (P).w);      \
            const bool ca2 = da < a2, ca1 = da < a1, ca0 = da < a0;        \
            { const int t = ca2 ? (GI) : ia2; ia2 = ca1 ? ia1 : t; }       \
            { const int t = ca1 ? (GI) : ia1; ia1 = ca0 ? ia0 : t; }       \
            ia0 = ca0 ? (GI) : ia0;                                        \
            const float na1 = __builtin_amdgcn_fmed3f(da, a0, a1);         \
            const float na2 = __builtin_amdgcn_fmed3f(da, a1, a2);         \
            a0 = fminf(a0, da); a1 = na1; a2 = na2;                        \
            const float crb = (bx * (P).x + by * (P).y) + bz * (P).z;      \
            const float db  = __builtin_fmaf(-2.0f, crb, bu + (P).w);      \
            const bool cb2 = db < b2, cb1 = db < b1, cb0 = db < b0;        \
            { const int t = cb2 ? (GI) : ib2; ib2 = cb1 ? ib1 : t; }       \
            { const int t = cb1 ? (GI) : ib1; ib1 = cb0 ? ib0 : t; }       \
            ib0 = cb0 ? (GI) : ib0;                                        \
            const float nb1 = __builtin_amdgcn_fmed3f(db, b0, b1);         \
            const float nb2 = __builtin_amdgcn_fmed3f(db, b1, b2);         \
            b0 = fminf(b0, db); b1 = nb1; b2 = nb2;                        \
        }

#pragma unroll 1
        for (int mg = 0; mg < CH; mg += 4) {
            const int nx = (mg + 4 < CH) ? (mg + 4) : 0;
            const f4v p0 = sp[nx], p1 = sp[nx + 1], p2 = sp[nx + 2], p3 = sp[nx + 3];
            PAIR(c0, mbase + mg + 0);
            PAIR(c1, mbase + mg + 1);
            PAIR(c2, mbase + mg + 2);
            PAIR(c3, mbase + mg + 3);
            c0 = p0; c1 = p1; c2 = p2; c3 = p3;
        }
#undef PAIR

        float* pd = part_d + (size_t)g0 * (S_CHUNKS * 3) + s * 3;
        int*   pi = part_i + (size_t)g0 * (S_CHUNKS * 3) + s * 3;
        pd[0] = a0; pd[1] = a1; pd[2] = a2;
        pi[0] = ia0; pi[1] = ia1; pi[2] = ia2;
        pd = part_d + (size_t)g1 * (S_CHUNKS * 3) + s * 3;
        pi = part_i + (size_t)g1 * (S_CHUNKS * 3) + s * 3;
        pd[0] = b0; pd[1] = b1; pd[2] = b2;
        pi[0] = ib0; pi[1] = ib1; pi[2] = ib2;
    } else {
        // ---- down-GEMM tile: 128x128, BK=64, K=N=512 ----
        const int blk  = blockIdx.x - KNN_BLOCKS;
        const int n0   = (blk & 3) * 128;
        const int m0   = (blk >> 2) * 128;
        const int tid  = threadIdx.x;
        const int lane = tid & 63;
        const int wv   = tid >> 6;
        const int wrow = (wv >> 1) * 64;
        const int wcol = (wv & 1) * 64;
        const int quad = lane >> 4;
        const int l16  = lane & 15;
        constexpr int K = C_DOWN_;   // 512
        constexpr int N = C_OUT_;    // 512

        f32x4 acc[4][4];
#pragma unroll
        for (int i = 0; i < 4; ++i)
#pragma unroll
            for (int j = 0; j < 4; ++j) {
                acc[i][j][0] = 0.f; acc[i][j][1] = 0.f;
                acc[i][j][2] = 0.f; acc[i][j][3] = 0.f;
            }

        const int o0 = wv * 4096 + lane * 16;

        for (int k0 = 0; k0 < K; k0 += 64) {
            __syncthreads();
#pragma unroll
            for (int c = 0; c < 4; ++c) {
                const int o  = o0 + c * 1024;
                const int r  = o >> 7;          // row in tile
                const int ke = (o & 127) >> 1;  // bf16 elem index in row
                const float4 va0 = *(const float4*)(Af + (size_t)(m0 + r) * K + k0 + ke);
                const float4 va1 = *(const float4*)(Af + (size_t)(m0 + r) * K + k0 + ke + 4);
                *(uint4*)((char*)As + o) = pack8(va0, va1);
                const float4 vb0 = *(const float4*)(Wf + (size_t)(n0 + r) * K + k0 + ke);
                const float4 vb1 = *(const float4*)(Wf + (size_t)(n0 + r) * K + k0 + ke + 4);
                *(uint4*)((char*)Bs + o) = pack8(vb0, vb1);
            }
            __syncthreads();

#pragma unroll
            for (int kk = 0; kk < 2; ++kk) {
                bf16x8 af[4], bw[4];
#pragma unroll
                for (int i = 0; i < 4; ++i)
                    af[i] = *(const bf16x8*)(As + (wrow + i * 16 + l16) * 64 + kk * 32 + quad * 8);
#pragma unroll
                for (int j = 0; j < 4; ++j)
                    bw[j] = *(const bf16x8*)(Bs + (wcol + j * 16 + l16) * 64 + kk * 32 + quad * 8);
#pragma unroll
                for (int i = 0; i < 4; ++i)
#pragma unroll
                    for (int j = 0; j < 4; ++j)
                        acc[i][j] = __builtin_amdgcn_mfma_f32_16x16x32_bf16(
                            af[i], bw[j], acc[i][j], 0, 0, 0);
            }
        }

        float bv[4];
#pragma unroll
        for (int j = 0; j < 4; ++j) bv[j] = bias[n0 + wcol + j * 16 + l16];

#pragma unroll
        for (int i = 0; i < 4; ++i) {
#pragma unroll
            for (int r = 0; r < 4; ++r) {
                const int row = m0 + wrow + i * 16 + quad * 4 + r;
                float* crow = C + (size_t)row * N;
#pragma unroll
                for (int j = 0; j < 4; ++j) {
                    const int c = n0 + wcol + j * 16 + l16;
                    crow[c] = acc[i][j][r] + bv[j];
                }
            }
        }
    }
}

// ---------------------------------------------------------------------------
// Merge S*3 exact candidates (ascending chunk = ascending index => identical
// tie-breaks to the full scan), compute normalized inverse-distance weights.
// ---------------------------------------------------------------------------
__launch_bounds__(256)
__global__ void knn_merge(const float* __restrict__ part_d,
                          const int*   __restrict__ part_i,
                          int*  __restrict__ idx_out,   // [B*N_UP,3]
                          float* __restrict__ w_out)    // [B*N_UP,3]
{
    const int g = blockIdx.x * 256 + threadIdx.x;
    const float4* pd = (const float4*)(part_d + (size_t)g * (S_CHUNKS * 3));
    const int4*   pi = (const int4*)(part_i + (size_t)g * (S_CHUNKS * 3));

    float d0 = 1e30f, d1 = 1e30f, d2 = 1e30f;
    int   i0 = 0,     i1 = 0,     i2 = 0;

#pragma unroll
    for (int q = 0; q < (S_CHUNKS * 3) / 4; ++q) {
        const float4 dv = pd[q];
        const int4   iv = pi[q];
        const float dd[4] = {dv.x, dv.y, dv.z, dv.w};
        const int   ii[4] = {iv.x, iv.y, iv.z, iv.w};
#pragma unroll
        for (int j = 0; j < 4; ++j) {
            const float d = dd[j];
            const int   m = ii[j];
            const bool c2 = d < d2;
            const bool c1 = d < d1;
            const bool c0 = d < d0;
            { const int t = c2 ? m : i2; i2 = c1 ? i1 : t; }
            { const int t = c1 ? m : i1; i1 = c0 ? i0 : t; }
            i0 = c0 ? m : i0;
            const float nd1 = __builtin_amdgcn_fmed3f(d, d0, d1);
            const float nd2 = __builtin_amdgcn_fmed3f(d, d1, d2);
            d0 = fminf(d0, d);
            d1 = nd1;
            d2 = nd2;
        }
    }

    const float w0 = 1.0f / (d0 + 1e-8f);
    const float w1 = 1.0f / (d1 + 1e-8f);
    const float w2 = 1.0f / (d2 + 1e-8f);
    const float s  = (w0 + w1) + w2;
    idx_out[(size_t)g * 3 + 0] = i0;
    idx_out[(size_t)g * 3 + 1] = i1;
    idx_out[(size_t)g * 3 + 2] = i2;
    w_out[(size_t)g * 3 + 0] = w0 / s;
    w_out[(size_t)g * 3 + 1] = w1 / s;
    w_out[(size_t)g * 3 + 2] = w2 / s;
}

// ---------------------------------------------------------------------------
// up-GEMM + interp gather epilogue: out = upf @ Wup^T + b_up + sum w_i*down_f[idx_i]
// 128x128 tile, BK=64, K=384, N=512; staged from f32 with inline f2bf
// (bit-identical LDS contents vs the R7 bf16-buffer version).
// ---------------------------------------------------------------------------
__launch_bounds__(256)
__global__ void gemm_interp(const float* __restrict__ Af,       // up_features f32 [B*N_UP, 384]
                            const float* __restrict__ Wf,       // W_up f32 [512, 384]
                            const float* __restrict__ bias,     // b_up
                            float* __restrict__ C,              // out [B*N_UP, 512]
                            const int* __restrict__ knn_idx,    // [B*N_UP,3]
                            const float* __restrict__ knn_w,    // [B*N_UP,3]
                            const float* __restrict__ down_f)   // [B*N_DOWN, 512]
{
    __shared__ __align__(16) unsigned short As[128 * 64];   // 16 KB
    __shared__ __align__(16) unsigned short Bs[128 * 64];   // 16 KB
    __shared__ int   sI[128 * 3];
    __shared__ float sV[128 * 3];

    const int tid  = threadIdx.x;
    const int lane = tid & 63;
    const int wv   = tid >> 6;
    const int wrow = (wv >> 1) * 64;
    const int wcol = (wv & 1) * 64;
    const int quad = lane >> 4;
    const int l16  = lane & 15;
    const int m0   = blockIdx.y * 128;
    const int n0   = blockIdx.x * 128;
    constexpr int K = C_UP_;    // 384
    constexpr int N = C_OUT_;   // 512

    for (int t = tid; t < 384; t += 256) {
        sI[t] = knn_idx[(size_t)m0 * 3 + t];
        sV[t] = knn_w[(size_t)m0 * 3 + t];
    }

    f32x4 acc[4][4];
#pragma unroll
    for (int i = 0; i < 4; ++i)
#pragma unroll
        for (int j = 0; j < 4; ++j) {
            acc[i][j][0] = 0.f; acc[i][j][1] = 0.f;
            acc[i][j][2] = 0.f; acc[i][j][3] = 0.f;
        }

    const int o0 = wv * 4096 + lane * 16;

    for (int k0 = 0; k0 < K; k0 += 64) {
        __syncthreads();
#pragma unroll
        for (int c = 0; c < 4; ++c) {
            const int o  = o0 + c * 1024;
            const int r  = o >> 7;
            const int ke = (o & 127) >> 1;
            const float4 va0 = *(const float4*)(Af + (size_t)(m0 + r) * K + k0 + ke);
            const float4 va1 = *(const float4*)(Af + (size_t)(m0 + r) * K + k0 + ke + 4);
            *(uint4*)((char*)As + o) = pack8(va0, va1);
            const float4 vb0 = *(const float4*)(Wf + (size_t)(n0 + r) * K + k0 + ke);
            const float4 vb1 = *(const float4*)(Wf + (size_t)(n0 + r) * K + k0 + ke + 4);
            *(uint4*)((char*)Bs + o) = pack8(vb0, vb1);
        }
        __syncthreads();

#pragma unroll
        for (int kk = 0; kk < 2; ++kk) {
            bf16x8 af[4], bw[4];
#pragma unroll
            for (int i = 0; i < 4; ++i)
                af[i] = *(const bf16x8*)(As + (wrow + i * 16 + l16) * 64 + kk * 32 + quad * 8);
#pragma unroll
            for (int j = 0; j < 4; ++j)
                bw[j] = *(const bf16x8*)(Bs + (wcol + j * 16 + l16) * 64 + kk * 32 + quad * 8);
#pragma unroll
            for (int i = 0; i < 4; ++i)
#pragma unroll
                for (int j = 0; j < 4; ++j)
                    acc[i][j] = __builtin_amdgcn_mfma_f32_16x16x32_bf16(
                        af[i], bw[j], acc[i][j], 0, 0, 0);
        }
    }

    float bv[4];
#pragma unroll
    for (int j = 0; j < 4; ++j) bv[j] = bias[n0 + wcol + j * 16 + l16];

#pragma unroll
    for (int i = 0; i < 4; ++i) {
#pragma unroll
        for (int r = 0; r < 4; ++r) {
            const int row = m0 + wrow + i * 16 + quad * 4 + r;  // C/D: row=quad*4+reg
            float* crow = C + (size_t)row * N;
            const int lr3  = (row - m0) * 3;
            const int base = (row >> 14) * N_DOWN;              // batch * N_DOWN
            const float w0 = sV[lr3 + 0], w1 = sV[lr3 + 1], w2 = sV[lr3 + 2];
            const float* f0 = down_f + (size_t)(base + sI[lr3 + 0]) * N;
            const float* f1 = down_f + (size_t)(base + sI[lr3 + 1]) * N;
            const float* f2 = down_f + (size_t)(base + sI[lr3 + 2]) * N;
#pragma unroll
            for (int j = 0; j < 4; ++j) {
                const int c = n0 + wcol + j * 16 + l16;         // C/D: col=lane&15
                crow[c] = acc[i][j][r] + bv[j] + w0 * f0[c] + w1 * f1[c] + w2 * f2[c];
            }
        }
    }
}

// ---------------------------------------------------------------------------
extern "C" void kernel_launch(void* const* d_in, const int* in_sizes, int n_in,
                              void* d_out, int out_size, void* d_ws, size_t ws_size,
                              hipStream_t stream) {
    const float* up_points     = (const float*)d_in[0];
    const float* up_features   = (const float*)d_in[1];
    const float* down_points   = (const float*)d_in[2];
    const float* down_features = (const float*)d_in[3];
    const float* W_up          = (const float*)d_in[4];
    const float* b_up          = (const float*)d_in[5];
    const float* W_down        = (const float*)d_in[6];
    const float* b_down        = (const float*)d_in[7];
    float* out = (float*)d_out;

    // workspace layout (all offsets 256B-aligned by construction)
    char* ws = (char*)d_ws;
    size_t off = 0;
    float* down_f = (float*)(ws + off);             off += (size_t)B_ * N_DOWN * C_OUT_ * 4;      // 33.6 MB
    int*   knn_idx = (int*)(ws + off);              off += (size_t)B_ * N_UP * 3 * 4;             // 0.8 MB
    float* knn_w   = (float*)(ws + off);            off += (size_t)B_ * N_UP * 3 * 4;             // 0.8 MB
    float* part_d  = (float*)(ws + off);            off += (size_t)B_ * N_UP * S_CHUNKS * 3 * 4;  // 12.6 MB
    int*   part_i  = (int*)(ws + off);              off += (size_t)B_ * N_UP * S_CHUNKS * 3 * 4;  // 12.6 MB
    float4* pts4   = (float4*)(ws + off);           off += (size_t)B_ * N_DOWN * 16;              // 0.26 MB

    // 1) points prep
    prep_pts4<<<(B_ * N_DOWN) / 256, 256, 0, stream>>>(down_points, pts4);

    // 2) fused brute-knn + down-GEMM (independent; gemm backfills knn's tail)
    knn_gdown<<<KNN_BLOCKS + GF_BLOCKS, 256, 0, stream>>>(
        up_points, pts4, part_d, part_i,
        down_features, W_down, b_down, down_f);

    // 3) merge partial top-3s -> knn_idx / knn_w
    knn_merge<<<(B_ * N_UP) / 256, 256, 0, stream>>>(part_d, part_i, knn_idx, knn_w);

    // 4) out = upf @ Wup^T + b_up + interp(down_f)
    gemm_interp<<<dim3(C_OUT_ / 128, (B_ * N_UP) / 128), 256, 0, stream>>>(
        up_features, W_up, b_up, out, knn_idx, knn_w, down_f);
}

// Round 10
// 437.852 us; speedup vs baseline: 2.0704x; 1.0802x over previous
//
#include <hip/hip_runtime.h>

// Problem constants (from reference)
constexpr int B_     = 4;
constexpr int N_UP   = 16384;
constexpr int N_DOWN = 4096;
constexpr int C_UP_  = 384;
constexpr int C_DOWN_= 512;
constexpr int C_OUT_ = 512;

// KNN chunking
constexpr int S_CHUNKS = 16;               // candidate chunks
constexpr int CH       = N_DOWN / S_CHUNKS; // 256 candidates per chunk

// Fused knn+cvt dispatch geometry
constexpr int KNN_BLOCKS     = (N_UP / 512) * B_ * S_CHUNKS;     // 2048
constexpr int CVT_BLOCKS_TOT = 24576 + 8192 + 192 + 256;         // 33216

typedef __attribute__((ext_vector_type(8))) short bf16x8;
typedef __attribute__((ext_vector_type(4))) float f32x4;
typedef __attribute__((ext_vector_type(4))) float f4v;

// f32 -> bf16 round-to-nearest-even (bit-exact, no API dependence)
__device__ inline unsigned short f2bf(float f) {
    unsigned int u = __float_as_uint(f);
    return (unsigned short)((u + 0x7FFFu + ((u >> 16) & 1u)) >> 16);
}

// async global->LDS, 16B per lane. HW: dest = wave-uniform base + lane*16.
__device__ inline void load_lds_128(const void* g, void* l) {
    __builtin_amdgcn_global_load_lds(
        (const __attribute__((address_space(1))) unsigned int*)g,
        (__attribute__((address_space(3))) unsigned int*)l, 16, 0, 0);
}

// ---------------------------------------------------------------------------
// pts4[b][m] = {x, y, z, (x*x+y*y)+z*z}   (ref rounding order, no contract)
// ---------------------------------------------------------------------------
__global__ void prep_pts4(const float* __restrict__ down_pts, float4* __restrict__ pts4) {
#pragma clang fp contract(off)
    const int i = blockIdx.x * 256 + threadIdx.x;   // 0 .. B*N_DOWN-1
    const float x = down_pts[i * 3 + 0];
    const float y = down_pts[i * 3 + 1];
    const float z = down_pts[i * 3 + 2];
    float4 p; p.x = x; p.y = y; p.z = z; p.w = (x * x + y * y) + z * z;
    pts4[i] = p;
}

// ---------------------------------------------------------------------------
// FUSED phase-1: brute knn chunk scan (blocks [0,2048)) + f32->bf16 cvt.
// Both paths LDS-free and independent; cvt backfills knn's latency shadow.
// knn body byte-identical to the R5/R6/R7 passing version.
// ---------------------------------------------------------------------------
__launch_bounds__(256, 8)
__global__ void knn_cvt(const float* __restrict__ up_pts,   // [B,N_UP,3]
                        const float4* __restrict__ pts4,    // [B,N_DOWN]
                        float* __restrict__ part_d,         // [B*N_UP, S*3]
                        int*   __restrict__ part_i,
                        const float* __restrict__ s_upf, unsigned short* __restrict__ d_upf,
                        const float* __restrict__ s_dnf, unsigned short* __restrict__ d_dnf,
                        const float* __restrict__ s_wup, unsigned short* __restrict__ d_wup,
                        const float* __restrict__ s_wdn, unsigned short* __restrict__ d_wdn)
{
    if (blockIdx.x < KNN_BLOCKS) {
#pragma clang fp contract(off)
        const int kb = blockIdx.x;
        const int b  = (kb >> 5) & 3;
        const int s  = kb >> 7;
        const int mbase = s * CH;

        typedef __attribute__((address_space(4))) const f4v cst_f4;
        const cst_f4* sp = (const cst_f4*)(pts4 + (size_t)b * N_DOWN + mbase);

        const int n0 = (kb & 31) * 512;
        const int g0 = b * N_UP + n0 + threadIdx.x;
        const int g1 = g0 + 256;

        const float ax = up_pts[(size_t)g0 * 3 + 0];
        const float ay = up_pts[(size_t)g0 * 3 + 1];
        const float az = up_pts[(size_t)g0 * 3 + 2];
        const float au = (ax * ax + ay * ay) + az * az;
        const float bx = up_pts[(size_t)g1 * 3 + 0];
        const float by = up_pts[(size_t)g1 * 3 + 1];
        const float bz = up_pts[(size_t)g1 * 3 + 2];
        const float bu = (bx * bx + by * by) + bz * bz;

        float a0 = 1e30f, a1 = 1e30f, a2 = 1e30f;  int ia0 = 0, ia1 = 0, ia2 = 0;
        float b0 = 1e30f, b1 = 1e30f, b2 = 1e30f;  int ib0 = 0, ib1 = 0, ib2 = 0;

        // prefetch double-buffer: group of 4 candidates = 64B scalar load
        f4v c0 = sp[0], c1 = sp[1], c2 = sp[2], c3 = sp[3];

#define PAIR(P, GI)                                                        \
        {                                                                  \
            const float cra = (ax * (P).x + ay * (P).y) + az * (P).z;      \
            const float da  = __builtin_fmaf(-2.0f, cra, au + (P).w);      \
            const bool ca2 = da < a2, ca1 = da < a1, ca0 = da < a0;        \
            { const int t = ca2 ? (GI) : ia2; ia2 = ca1 ? ia1 : t; }       \
            { const int t = ca1 ? (GI) : ia1; ia1 = ca0 ? ia0 : t; }       \
            ia0 = ca0 ? (GI) : ia0;                                        \
            const float na1 = __builtin_amdgcn_fmed3f(da, a0, a1);         \
            const float na2 = __builtin_amdgcn_fmed3f(da, a1, a2);         \
            a0 = fminf(a0, da); a1 = na1; a2 = na2;                        \
            const float crb = (bx * (P).x + by * (P).y) + bz * (P).z;      \
            const float db  = __builtin_fmaf(-2.0f, crb, bu + (P).w);      \
            const bool cb2 = db < b2, cb1 = db < b1, cb0 = db < b0;        \
            { const int t = cb2 ? (GI) : ib2; ib2 = cb1 ? ib1 : t; }       \
            { const int t = cb1 ? (GI) : ib1; ib1 = cb0 ? ib0 : t; }       \
            ib0 = cb0 ? (GI) : ib0;                                        \
            const float nb1 = __builtin_amdgcn_fmed3f(db, b0, b1);         \
            const float nb2 = __builtin_amdgcn_fmed3f(db, b1, b2);         \
            b0 = fminf(b0, db); b1 = nb1; b2 = nb2;                        \
        }

#pragma unroll 1
        for (int mg = 0; mg < CH; mg += 4) {
            const int nx = (mg + 4 < CH) ? (mg + 4) : 0;
            const f4v p0 = sp[nx], p1 = sp[nx + 1], p2 = sp[nx + 2], p3 = sp[nx + 3];
            PAIR(c0, mbase + mg + 0);
            PAIR(c1, mbase + mg + 1);
            PAIR(c2, mbase + mg + 2);
            PAIR(c3, mbase + mg + 3);
            c0 = p0; c1 = p1; c2 = p2; c3 = p3;
        }
#undef PAIR

        float* pd = part_d + (size_t)g0 * (S_CHUNKS * 3) + s * 3;
        int*   pi = part_i + (size_t)g0 * (S_CHUNKS * 3) + s * 3;
        pd[0] = a0; pd[1] = a1; pd[2] = a2;
        pi[0] = ia0; pi[1] = ia1; pi[2] = ia2;
        pd = part_d + (size_t)g1 * (S_CHUNKS * 3) + s * 3;
        pi = part_i + (size_t)g1 * (S_CHUNKS * 3) + s * 3;
        pd[0] = b0; pd[1] = b1; pd[2] = b2;
        pi[0] = ib0; pi[1] = ib1; pi[2] = ib2;
    } else {
        // cvt path: 1024 f32 elements per block, block-uniform buffer select
        const int blk = blockIdx.x - KNN_BLOCKS;
        const float* s; unsigned short* d; size_t base;
        if (blk < 24576)      { s = s_upf; d = d_upf; base = (size_t)blk * 1024; }
        else if (blk < 32768) { s = s_dnf; d = d_dnf; base = (size_t)(blk - 24576) * 1024; }
        else if (blk < 32960) { s = s_wup; d = d_wup; base = (size_t)(blk - 32768) * 1024; }
        else                  { s = s_wdn; d = d_wdn; base = (size_t)(blk - 32960) * 1024; }
        const size_t i = base / 4 + threadIdx.x;   // float4 index
        const float4 v = ((const float4*)s)[i];
        ushort4 o;
        o.x = f2bf(v.x); o.y = f2bf(v.y); o.z = f2bf(v.z); o.w = f2bf(v.w);
        ((ushort4*)d)[i] = o;
    }
}

// ---------------------------------------------------------------------------
// Merge S*3 exact candidates (ascending chunk = ascending index => identical
// tie-breaks to the full scan), compute normalized inverse-distance weights.
// ---------------------------------------------------------------------------
__launch_bounds__(256)
__global__ void knn_merge(const float* __restrict__ part_d,
                          const int*   __restrict__ part_i,
                          int*  __restrict__ idx_out,   // [B*N_UP,3]
                          float* __restrict__ w_out)    // [B*N_UP,3]
{
    const int g = blockIdx.x * 256 + threadIdx.x;
    const float4* pd = (const float4*)(part_d + (size_t)g * (S_CHUNKS * 3));
    const int4*   pi = (const int4*)(part_i + (size_t)g * (S_CHUNKS * 3));

    float d0 = 1e30f, d1 = 1e30f, d2 = 1e30f;
    int   i0 = 0,     i1 = 0,     i2 = 0;

#pragma unroll
    for (int q = 0; q < (S_CHUNKS * 3) / 4; ++q) {
        const float4 dv = pd[q];
        const int4   iv = pi[q];
        const float dd[4] = {dv.x, dv.y, dv.z, dv.w};
        const int   ii[4] = {iv.x, iv.y, iv.z, iv.w};
#pragma unroll
        for (int j = 0; j < 4; ++j) {
            const float d = dd[j];
            const int   m = ii[j];
            const bool c2 = d < d2;
            const bool c1 = d < d1;
            const bool c0 = d < d0;
            { const int t = c2 ? m : i2; i2 = c1 ? i1 : t; }
            { const int t = c1 ? m : i1; i1 = c0 ? i0 : t; }
            i0 = c0 ? m : i0;
            const float nd1 = __builtin_amdgcn_fmed3f(d, d0, d1);
            const float nd2 = __builtin_amdgcn_fmed3f(d, d1, d2);
            d0 = fminf(d0, d);
            d1 = nd1;
            d2 = nd2;
        }
    }

    const float w0 = 1.0f / (d0 + 1e-8f);
    const float w1 = 1.0f / (d1 + 1e-8f);
    const float w2 = 1.0f / (d2 + 1e-8f);
    const float s  = (w0 + w1) + w2;
    idx_out[(size_t)g * 3 + 0] = i0;
    idx_out[(size_t)g * 3 + 1] = i1;
    idx_out[(size_t)g * 3 + 2] = i2;
    w_out[(size_t)g * 3 + 0] = w0 / s;
    w_out[(size_t)g * 3 + 1] = w1 / s;
    w_out[(size_t)g * 3 + 2] = w2 / s;
}

// ---------------------------------------------------------------------------
// bf16 MFMA GEMM: C[m,n] = sum_k A[m,k]*W[n,k] (+bias) (+interp gather)
// 128x128 tile, BK=32 (19.4KB LDS -> 8 blocks/CU capacity), 4 waves,
// 16x16x32 MFMA, width-16 global_load_lds staging.
//
// T2 LDS swizzle, gload_lds-legal form (rule 21: linear dest + inverse-
// swizzled SOURCE + swizzled READ): LDS[row][col16] holds global element
// (row, col16 ^ (row&3)).  ds_read at col16 = quad ^ (l16&3) then yields
// global column quad (since row&3 == l16&3) -- data bit-identical, banks
// spread 8-way -> 4-way residual (was 16-way at BK=64: 9.4M conflicts, R7).
//
// XCD-aware bijective swizzle (nwg%8==0): each XCD gets a contiguous wg
// range; the 4 n-tiles sharing one 96KB A-panel run on the same XCD L2.
// ---------------------------------------------------------------------------
template<bool INTERP>
__launch_bounds__(256)
__global__ void gemm_bf16(const unsigned short* __restrict__ A,  // [M,K] bf16
                          const unsigned short* __restrict__ W,  // [N,K] bf16
                          const float* __restrict__ bias,        // [N]
                          float* __restrict__ C,                 // [M,N] f32
                          const int K, const int N,
                          const int* __restrict__ knn_idx,       // [M,3]
                          const float* __restrict__ knn_w,       // [M,3]
                          const float* __restrict__ down_f)      // [B*N_DOWN,N]
{
    __shared__ __align__(16) unsigned short As[128 * 32];   // 8 KB
    __shared__ __align__(16) unsigned short Bs[128 * 32];   // 8 KB
    __shared__ int   sI[128 * 3];
    __shared__ float sV[128 * 3];

    // XCD-aware swizzle: XCD i receives contiguous wg range [i*cpx,(i+1)*cpx)
    const int cpx = gridDim.x >> 3;
    const int lin = blockIdx.x;
    const int wg  = (lin & 7) * cpx + (lin >> 3);
    const int n0  = (wg & 3) * 128;          // N == 512 always here
    const int m0  = (wg >> 2) * 128;

    const int tid  = threadIdx.x;
    const int lane = tid & 63;
    const int wv   = tid >> 6;
    const int wrow = (wv >> 1) * 64;
    const int wcol = (wv & 1) * 64;
    const int quad = lane >> 4;
    const int l16  = lane & 15;

    if (INTERP) {
        for (int t = tid; t < 384; t += 256) {
            sI[t] = knn_idx[(size_t)m0 * 3 + t];
            sV[t] = knn_w[(size_t)m0 * 3 + t];
        }
    }

    f32x4 acc[4][4];
#pragma unroll
    for (int i = 0; i < 4; ++i)
#pragma unroll
        for (int j = 0; j < 4; ++j) {
            acc[i][j][0] = 0.f; acc[i][j][1] = 0.f;
            acc[i][j][2] = 0.f; acc[i][j][3] = 0.f;
        }

    // staging geometry: LDS tile [row][32k] bf16 (64B rows); wave covers 2KB
    // as two 1KB chunks of lane*16. Source column pre-swizzled: c ^ (row&3).
    const int o0 = wv * 2048 + lane * 16;
    const int o1 = o0 + 1024;                // +16 rows, same col16
    const int r0 = o0 >> 6, r1 = o1 >> 6;
    const int c16 = (o0 >> 4) & 3;
    const int sk  = ((c16 ^ (r0 & 3)) << 4); // r1&3 == r0&3, same sk
    const char* Ab = (const char*)A;
    const char* Wb = (const char*)W;
    const size_t Ks = (size_t)K;

    // swizzled fragment-read column: quad ^ (l16&3)
    const int sq8 = (quad ^ (l16 & 3)) * 8;

    for (int k0 = 0; k0 < K; k0 += 32) {
        __syncthreads();   // previous iter's ds_reads done before overwrite
        load_lds_128(Ab + ((size_t)(m0 + r0) * Ks + k0) * 2 + sk, (char*)As + o0);
        load_lds_128(Ab + ((size_t)(m0 + r1) * Ks + k0) * 2 + sk, (char*)As + o1);
        load_lds_128(Wb + ((size_t)(n0 + r0) * Ks + k0) * 2 + sk, (char*)Bs + o0);
        load_lds_128(Wb + ((size_t)(n0 + r1) * Ks + k0) * 2 + sk, (char*)Bs + o1);
        __syncthreads();   // vmcnt(0) drained by compiler before barrier

        bf16x8 af[4], bw[4];
#pragma unroll
        for (int i = 0; i < 4; ++i)
            af[i] = *(const bf16x8*)(As + (wrow + i * 16 + l16) * 32 + sq8);
#pragma unroll
        for (int j = 0; j < 4; ++j)
            bw[j] = *(const bf16x8*)(Bs + (wcol + j * 16 + l16) * 32 + sq8);
#pragma unroll
        for (int i = 0; i < 4; ++i)
#pragma unroll
            for (int j = 0; j < 4; ++j)
                acc[i][j] = __builtin_amdgcn_mfma_f32_16x16x32_bf16(
                    af[i], bw[j], acc[i][j], 0, 0, 0);
    }

    float bv[4];
#pragma unroll
    for (int j = 0; j < 4; ++j) bv[j] = bias[n0 + wcol + j * 16 + l16];

#pragma unroll
    for (int i = 0; i < 4; ++i) {
#pragma unroll
        for (int r = 0; r < 4; ++r) {
            const int row = m0 + wrow + i * 16 + quad * 4 + r;  // C/D: row=quad*4+reg
            float* crow = C + (size_t)row * N;
            if (INTERP) {
                const int lr3  = (row - m0) * 3;
                const int base = (row >> 14) * N_DOWN;          // batch * N_DOWN
                const float w0 = sV[lr3 + 0], w1 = sV[lr3 + 1], w2 = sV[lr3 + 2];
                const float* f0 = down_f + (size_t)(base + sI[lr3 + 0]) * N;
                const float* f1 = down_f + (size_t)(base + sI[lr3 + 1]) * N;
                const float* f2 = down_f + (size_t)(base + sI[lr3 + 2]) * N;
#pragma unroll
                for (int j = 0; j < 4; ++j) {
                    const int c = n0 + wcol + j * 16 + l16;     // C/D: col=lane&15
                    crow[c] = acc[i][j][r] + bv[j] + w0 * f0[c] + w1 * f1[c] + w2 * f2[c];
                }
            } else {
#pragma unroll
                for (int j = 0; j < 4; ++j) {
                    const int c = n0 + wcol + j * 16 + l16;
                    crow[c] = acc[i][j][r] + bv[j];
                }
            }
        }
    }
}

// ---------------------------------------------------------------------------
extern "C" void kernel_launch(void* const* d_in, const int* in_sizes, int n_in,
                              void* d_out, int out_size, void* d_ws, size_t ws_size,
                              hipStream_t stream) {
    const float* up_points     = (const float*)d_in[0];
    const float* up_features   = (const float*)d_in[1];
    const float* down_points   = (const float*)d_in[2];
    const float* down_features = (const float*)d_in[3];
    const float* W_up          = (const float*)d_in[4];
    const float* b_up          = (const float*)d_in[5];
    const float* W_down        = (const float*)d_in[6];
    const float* b_down        = (const float*)d_in[7];
    float* out = (float*)d_out;

    // workspace layout (all offsets 256B-aligned by construction)
    char* ws = (char*)d_ws;
    size_t off = 0;
    float* down_f = (float*)(ws + off);             off += (size_t)B_ * N_DOWN * C_OUT_ * 4;      // 33.6 MB
    int*   knn_idx = (int*)(ws + off);              off += (size_t)B_ * N_UP * 3 * 4;             // 0.8 MB
    float* knn_w   = (float*)(ws + off);            off += (size_t)B_ * N_UP * 3 * 4;             // 0.8 MB
    float* part_d  = (float*)(ws + off);            off += (size_t)B_ * N_UP * S_CHUNKS * 3 * 4;  // 12.6 MB
    int*   part_i  = (int*)(ws + off);              off += (size_t)B_ * N_UP * S_CHUNKS * 3 * 4;  // 12.6 MB
    float4* pts4   = (float4*)(ws + off);           off += (size_t)B_ * N_DOWN * 16;              // 0.26 MB
    unsigned short* upf_bf = (unsigned short*)(ws + off); off += (size_t)B_ * N_UP * C_UP_ * 2;   // 50.3 MB
    unsigned short* dnf_bf = (unsigned short*)(ws + off); off += (size_t)B_ * N_DOWN * C_DOWN_ * 2; // 16.8 MB
    unsigned short* wup_bf = (unsigned short*)(ws + off); off += (size_t)C_OUT_ * C_UP_ * 2;      // 0.4 MB
    unsigned short* wdn_bf = (unsigned short*)(ws + off); off += (size_t)C_OUT_ * C_DOWN_ * 2;    // 0.5 MB

    // 1) points prep
    prep_pts4<<<(B_ * N_DOWN) / 256, 256, 0, stream>>>(down_points, pts4);

    // 2) fused brute-knn + all f32->bf16 conversions (one dispatch)
    knn_cvt<<<KNN_BLOCKS + CVT_BLOCKS_TOT, 256, 0, stream>>>(
        up_points, pts4, part_d, part_i,
        up_features, upf_bf, down_features, dnf_bf, W_up, wup_bf, W_down, wdn_bf);

    // 3) merge partial top-3s
    knn_merge<<<(B_ * N_UP) / 256, 256, 0, stream>>>(part_d, part_i, knn_idx, knn_w);

    // 4) down_f = down_features @ W_down^T + b_down   [B*N_DOWN, 512]
    gemm_bf16<false><<<512, 256, 0, stream>>>(
        dnf_bf, wdn_bf, b_down, down_f, C_DOWN_, C_OUT_, nullptr, nullptr, nullptr);

    // 5) out = up_features @ W_up^T + b_up + interp(down_f)   [B*N_UP, 512]
    gemm_bf16<true><<<2048, 256, 0, stream>>>(
        upf_bf, wup_bf, b_up, out, C_UP_, C_OUT_, knn_idx, knn_w, down_f);
}